// Round 3
// baseline (536.309 us; speedup 1.0000x reference)
//
#include <hip/hip_runtime.h>
#include <hip/hip_bf16.h>
#include <cstdint>

#define BATCH 8192
#define DIM   128
#define MARGIN 1.0f

typedef __attribute__((ext_vector_type(8))) short short8;
typedef __attribute__((ext_vector_type(4))) float f32x4;

// ---------------------------------------------------------------------------
// Kernel 1: convert fp32 -> bf16, per-row squared norms (fp32-exact),
// init hp2 (max-accum) / hn2 (min-accum). One wave per row, 4 waves/block.
// ---------------------------------------------------------------------------
__global__ __launch_bounds__(256) void bhtl_prep(
    const float* __restrict__ emb,
    __hip_bfloat16* __restrict__ Ebf,
    float* __restrict__ sq,
    unsigned* __restrict__ hp2,
    unsigned* __restrict__ hn2)
{
    const int w   = threadIdx.x >> 6;
    const int l   = threadIdx.x & 63;
    const int row = blockIdx.x * 4 + w;
    const float2 e = ((const float2*)(emb + row * DIM))[l];
    __hip_bfloat162 h2;
    h2.x = __float2bfloat16(e.x);
    h2.y = __float2bfloat16(e.y);
    ((__hip_bfloat162*)(Ebf + row * DIM))[l] = h2;
    float s = e.x * e.x + e.y * e.y;
    #pragma unroll
    for (int d = 1; d < 64; d <<= 1) s += __shfl_xor(s, d, 64);
    if (l == 0) {
        sq[row]  = s;
        hp2[row] = 0u;           // max accumulator (non-negative domain)
        hn2[row] = 0x7F800000u;  // +inf
    }
}

// ---------------------------------------------------------------------------
// Kernel 2: fused E @ E^T + hardest-pos/neg selection.
// Barrier-free, LDS-free, software-pipelined.
// 512 blocks x 256 threads = 2048 waves (2/SIMD, all resident).
// Wave W: row band rb = W & 127 (64 rows, A frags PINNED in 64 VGPRs via
// empty inline-asm so the compiler cannot sink the loads into the loop),
// col split js = W >> 7 (512 cols, 16 steps of 32).
// B fragments double-buffered: step jt+1's loads issue before jt's MFMAs,
// so waits are partial vmcnt(N), not vmcnt(0).
// Block's 4 waves share js (same B sweep -> L1 reuse).
// ---------------------------------------------------------------------------
__global__ __launch_bounds__(256, 2) void bhtl_main(
    const __hip_bfloat16* __restrict__ Ebf,
    const float* __restrict__ sq,
    const int* __restrict__ labels,
    unsigned* __restrict__ hp2,
    unsigned* __restrict__ hn2)
{
    const int w    = threadIdx.x >> 6;
    const int lane = threadIdx.x & 63;
    const int W    = blockIdx.x * 4 + w;   // 0..2047
    const int rb   = W & 127;              // row band (64 rows)
    const int js   = W >> 7;               // 0..15 column split (512 cols)
    const int rowbase = rb * 64;
    const int jbase0  = js * 512;
    const int q  = lane >> 4;              // 0..3
    const int ln = lane & 15;              // 0..15

    // ---- A fragments (64 rows x K=128), loaded ONCE, pinned in VGPRs ----
    short8 af[4][4];
    #pragma unroll
    for (int m = 0; m < 4; ++m)
        #pragma unroll
        for (int kc = 0; kc < 4; ++kc) {
            af[m][kc] = *(const short8*)(Ebf + (rowbase + m * 16 + ln) * DIM + kc * 32 + q * 8);
            asm volatile("" : "+v"(af[m][kc]));   // opaque touch: cannot be re-materialized
        }

    // ---- anchor labels for this lane's 16 row slots (m*4 + r) ----
    int labi[16];
    #pragma unroll
    for (int m = 0; m < 4; ++m)
        #pragma unroll
        for (int r = 0; r < 4; ++r)
            labi[m * 4 + r] = labels[rowbase + m * 16 + q * 4 + r];

    float maxpos[16], minneg[16];
    #pragma unroll
    for (int s = 0; s < 16; ++s) { maxpos[s] = -INFINITY; minneg[s] = INFINITY; }

    // ---- B loader / compute step as lambdas over explicit register sets ----
    auto loadB = [&](short8 (&bfr)[2][4], float (&sqj)[2], int (&labj)[2], int jb) {
        #pragma unroll
        for (int n = 0; n < 2; ++n) {
            #pragma unroll
            for (int kc = 0; kc < 4; ++kc)
                bfr[n][kc] = *(const short8*)(Ebf + (jb + n * 16 + ln) * DIM + kc * 32 + q * 8);
            sqj[n]  = sq[jb + n * 16 + ln];
            labj[n] = labels[jb + n * 16 + ln];
        }
    };

    auto step = [&](const short8 (&bfr)[2][4], const float (&sqj)[2], const int (&labj)[2]) {
        const f32x4 zero = {0.f, 0.f, 0.f, 0.f};
        f32x4 acc[4][2];
        #pragma unroll
        for (int m = 0; m < 4; ++m)
            #pragma unroll
            for (int n = 0; n < 2; ++n) acc[m][n] = zero;
        #pragma unroll
        for (int kc = 0; kc < 4; ++kc)
            #pragma unroll
            for (int m = 0; m < 4; ++m)
                #pragma unroll
                for (int n = 0; n < 2; ++n)
                    acc[m][n] = __builtin_amdgcn_mfma_f32_16x16x32_bf16(
                        af[m][kc], bfr[n][kc], acc[m][n], 0, 0, 0);
        #pragma unroll
        for (int m = 0; m < 4; ++m)
            #pragma unroll
            for (int n = 0; n < 2; ++n)
                #pragma unroll
                for (int r = 0; r < 4; ++r) {
                    float val = fmaf(-2.0f, acc[m][n][r], sqj[n]);
                    bool same = (labi[m * 4 + r] == labj[n]);
                    maxpos[m * 4 + r] = fmaxf(maxpos[m * 4 + r], same ? val : -INFINITY);
                    minneg[m * 4 + r] = fminf(minneg[m * 4 + r], same ? INFINITY : val);
                }
    };

    // ---- software-pipelined sweep over 16 x 32-col steps ----
    short8 bA[2][4], bB[2][4];
    float  sqA[2], sqB[2];
    int    laA[2], laB[2];

    loadB(bA, sqA, laA, jbase0);
    #pragma unroll
    for (int p = 0; p < 8; ++p) {
        loadB(bB, sqB, laB, jbase0 + (2 * p + 1) * 32);
        step(bA, sqA, laA);
        if (p < 7) loadB(bA, sqA, laA, jbase0 + (2 * p + 2) * 32);
        step(bB, sqB, laB);
    }

    // ---- reduce across the 16 ln-lanes sharing each row, then atomics ----
    #pragma unroll
    for (int s = 0; s < 16; ++s) {
        float mp = maxpos[s], mn = minneg[s];
        #pragma unroll
        for (int d = 1; d < 16; d <<= 1) {
            mp = fmaxf(mp, __shfl_xor(mp, d, 64));
            mn = fminf(mn, __shfl_xor(mn, d, 64));
        }
        if (ln == 0) {
            int row = rowbase + (s >> 2) * 16 + q * 4 + (s & 3);
            float sqi = sq[row];
            float hp2c = fmaxf(sqi + mp, 0.0f);   // clamp >=0: uint order == float order
            float hn2c = fmaxf(sqi + mn, 0.0f);
            atomicMax(&hp2[row], __float_as_uint(hp2c));
            atomicMin(&hn2[row], __float_as_uint(hn2c));
        }
    }
}

// ---------------------------------------------------------------------------
// Kernel 3: per-anchor loss + mean. Single block, deterministic output.
// ---------------------------------------------------------------------------
__global__ __launch_bounds__(1024) void bhtl_final(
    const unsigned* __restrict__ hp2,
    const unsigned* __restrict__ hn2,
    float* __restrict__ out)
{
    __shared__ float red[16];
    float sum = 0.f;
    for (int i = threadIdx.x; i < BATCH; i += 1024) {
        float hp = sqrtf(__uint_as_float(hp2[i]));
        float hn = sqrtf(__uint_as_float(hn2[i]));
        sum += fmaxf(hp - hn + MARGIN, 0.f);
    }
    #pragma unroll
    for (int d = 1; d < 64; d <<= 1) sum += __shfl_xor(sum, d, 64);
    int wv = threadIdx.x >> 6;
    if ((threadIdx.x & 63) == 0) red[wv] = sum;
    __syncthreads();
    if (threadIdx.x < 64) {
        float v = (threadIdx.x < 16) ? red[threadIdx.x] : 0.f;
        #pragma unroll
        for (int d = 1; d < 16; d <<= 1) v += __shfl_xor(v, d, 64);
        if (threadIdx.x == 0) out[0] = v / (float)BATCH;
    }
}

// ---------------------------------------------------------------------------
extern "C" void kernel_launch(void* const* d_in, const int* in_sizes, int n_in,
                              void* d_out, int out_size, void* d_ws, size_t ws_size,
                              hipStream_t stream)
{
    const float* emb    = (const float*)d_in[0];
    const int*   labels = (const int*)d_in[1];
    float*       out    = (float*)d_out;

    char* ws = (char*)d_ws;
    __hip_bfloat16* Ebf = (__hip_bfloat16*)ws;                       // 2 MiB
    float*    sq  = (float*)   (ws + 2 * 1024 * 1024);               // 32 KiB
    unsigned* hp2 = (unsigned*)(ws + 2 * 1024 * 1024 + 32 * 1024);   // 32 KiB
    unsigned* hn2 = (unsigned*)(ws + 2 * 1024 * 1024 + 64 * 1024);   // 32 KiB

    bhtl_prep<<<BATCH / 4, 256, 0, stream>>>(emb, Ebf, sq, hp2, hn2);
    bhtl_main<<<512, 256, 0, stream>>>(Ebf, sq, labels, hp2, hn2);
    bhtl_final<<<1, 1024, 0, stream>>>(hp2, hn2, out);
}

// Round 4
// 132.250 us; speedup vs baseline: 4.0553x; 4.0553x over previous
//
#include <hip/hip_runtime.h>
#include <hip/hip_bf16.h>
#include <cstdint>

#define BATCH 8192
#define DIM   128
#define MARGIN 1.0f

typedef __attribute__((ext_vector_type(8))) short short8;
typedef __attribute__((ext_vector_type(4))) float f32x4;
typedef __attribute__((ext_vector_type(4))) int   i32x4;

// ---------------------------------------------------------------------------
// Kernel 1: convert fp32 -> bf16, per-row squared norms (fp32-exact),
// init hp2 (max-accum) / hn2 (min-accum). One wave per row, 4 waves/block.
// ---------------------------------------------------------------------------
__global__ __launch_bounds__(256) void bhtl_prep(
    const float* __restrict__ emb,
    __hip_bfloat16* __restrict__ Ebf,
    float* __restrict__ sq,
    unsigned* __restrict__ hp2,
    unsigned* __restrict__ hn2)
{
    const int w   = threadIdx.x >> 6;
    const int l   = threadIdx.x & 63;
    const int row = blockIdx.x * 4 + w;
    const float2 e = ((const float2*)(emb + row * DIM))[l];
    __hip_bfloat162 h2;
    h2.x = __float2bfloat16(e.x);
    h2.y = __float2bfloat16(e.y);
    ((__hip_bfloat162*)(Ebf + row * DIM))[l] = h2;
    float s = e.x * e.x + e.y * e.y;
    #pragma unroll
    for (int d = 1; d < 64; d <<= 1) s += __shfl_xor(s, d, 64);
    if (l == 0) {
        sq[row]  = s;
        hp2[row] = 0u;           // max accumulator (non-negative domain)
        hn2[row] = 0x7F800000u;  // +inf
    }
}

// ---------------------------------------------------------------------------
// Kernel 2: fused E @ E^T + hardest-pos/neg selection. Barrier-free, no LDS.
// TRANSPOSED MFMA: acc = mfma(bf, af, acc) so lane (q,ln) element r maps to
//   anchor row = rowbase + m*16 + ln   (one row per lane per m-block!)
//   col        = jb + n*16 + q*4 + r
// -> per-row select state is tiny: mp/mn = 2 regs each, labi = 2 regs.
// Wave: 32-row band (af pinned, 32 VGPRs), sweeps 512 cols in 16x32 steps.
// 1024 blocks x 256 thr = 4096 waves = 4 waves/SIMD at <=128 VGPR.
// Block's 4 waves = 4 adjacent row bands x SAME col sweep -> L1 reuse.
// Register census ~118: af 32 + bf 32 + acc 16 + sqj/labj 16 + state/addr ~22.
// ---------------------------------------------------------------------------
__global__ __launch_bounds__(256, 4) void bhtl_main(
    const __hip_bfloat16* __restrict__ Ebf,
    const float* __restrict__ sq,
    const int* __restrict__ labels,
    unsigned* __restrict__ hp2,
    unsigned* __restrict__ hn2)
{
    const int w    = threadIdx.x >> 6;
    const int lane = threadIdx.x & 63;
    const int q    = lane >> 4;            // 0..3
    const int ln   = lane & 15;            // 0..15
    const int cs   = blockIdx.x & 15;      // col split (512 cols)
    const int rg   = blockIdx.x >> 4;      // row group (4 bands of 32)
    const int rowbase = (rg * 4 + w) * 32;
    const int jbase0  = cs * 512;

    // ---- A fragments (32 rows x K=128), loaded once, pinned in VGPRs ----
    short8 af[2][4];
    #pragma unroll
    for (int m = 0; m < 2; ++m)
        #pragma unroll
        for (int kc = 0; kc < 4; ++kc) {
            af[m][kc] = *(const short8*)(Ebf + (rowbase + m * 16 + ln) * DIM + kc * 32 + q * 8);
            asm("" : "+v"(af[m][kc]));     // opaque: cannot be rematerialized
        }

    int labi[2];
    #pragma unroll
    for (int m = 0; m < 2; ++m) {
        labi[m] = labels[rowbase + m * 16 + ln];
        asm("" : "+v"(labi[m]));
    }

    float mp[2] = {-INFINITY, -INFINITY};
    float mn[2] = { INFINITY,  INFINITY};

    #pragma unroll 1
    for (int jt = 0; jt < 16; ++jt) {
        const int jb = jbase0 + jt * 32;

        short8 bf[2][4];
        f32x4  sqj[2];
        i32x4  labj[2];
        #pragma unroll
        for (int n = 0; n < 2; ++n) {
            #pragma unroll
            for (int kc = 0; kc < 4; ++kc)
                bf[n][kc] = *(const short8*)(Ebf + (jb + n * 16 + ln) * DIM + kc * 32 + q * 8);
            sqj[n]  = *(const f32x4*)(sq     + jb + n * 16 + q * 4);
            labj[n] = *(const i32x4*)(labels + jb + n * 16 + q * 4);
        }

        f32x4 acc[2][2];
        const f32x4 zero = {0.f, 0.f, 0.f, 0.f};
        #pragma unroll
        for (int m = 0; m < 2; ++m)
            #pragma unroll
            for (int n = 0; n < 2; ++n) acc[m][n] = zero;

        #pragma unroll
        for (int kc = 0; kc < 4; ++kc)
            #pragma unroll
            for (int m = 0; m < 2; ++m)
                #pragma unroll
                for (int n = 0; n < 2; ++n)
                    acc[m][n] = __builtin_amdgcn_mfma_f32_16x16x32_bf16(
                        bf[n][kc], af[m][kc], acc[m][n], 0, 0, 0);   // transposed

        #pragma unroll
        for (int m = 0; m < 2; ++m)
            #pragma unroll
            for (int n = 0; n < 2; ++n)
                #pragma unroll
                for (int r = 0; r < 4; ++r) {
                    float val = fmaf(-2.0f, acc[m][n][r], sqj[n][r]);
                    bool same = (labi[m] == labj[n][r]);
                    mp[m] = fmaxf(mp[m], same ? val : -INFINITY);
                    mn[m] = fminf(mn[m], same ? INFINITY : val);
                }
    }

    // ---- reduce over the 4 q-lanes sharing each row, then atomics ----
    #pragma unroll
    for (int m = 0; m < 2; ++m) {
        float a = mp[m], b = mn[m];
        a = fmaxf(a, __shfl_xor(a, 16, 64));
        a = fmaxf(a, __shfl_xor(a, 32, 64));
        b = fminf(b, __shfl_xor(b, 16, 64));
        b = fminf(b, __shfl_xor(b, 32, 64));
        if (q == 0) {
            int row = rowbase + m * 16 + ln;
            float s = sq[row];
            float hp2c = fmaxf(s + a, 0.0f);   // clamp>=0: uint order == float order
            float hn2c = fmaxf(s + b, 0.0f);
            atomicMax(&hp2[row], __float_as_uint(hp2c));
            atomicMin(&hn2[row], __float_as_uint(hn2c));
        }
    }
}

// ---------------------------------------------------------------------------
// Kernel 3: per-anchor loss + mean. Single block, deterministic output.
// ---------------------------------------------------------------------------
__global__ __launch_bounds__(1024) void bhtl_final(
    const unsigned* __restrict__ hp2,
    const unsigned* __restrict__ hn2,
    float* __restrict__ out)
{
    __shared__ float red[16];
    float sum = 0.f;
    for (int i = threadIdx.x; i < BATCH; i += 1024) {
        float hp = sqrtf(__uint_as_float(hp2[i]));
        float hn = sqrtf(__uint_as_float(hn2[i]));
        sum += fmaxf(hp - hn + MARGIN, 0.f);
    }
    #pragma unroll
    for (int d = 1; d < 64; d <<= 1) sum += __shfl_xor(sum, d, 64);
    int wv = threadIdx.x >> 6;
    if ((threadIdx.x & 63) == 0) red[wv] = sum;
    __syncthreads();
    if (threadIdx.x < 64) {
        float v = (threadIdx.x < 16) ? red[threadIdx.x] : 0.f;
        #pragma unroll
        for (int d = 1; d < 16; d <<= 1) v += __shfl_xor(v, d, 64);
        if (threadIdx.x == 0) out[0] = v / (float)BATCH;
    }
}

// ---------------------------------------------------------------------------
extern "C" void kernel_launch(void* const* d_in, const int* in_sizes, int n_in,
                              void* d_out, int out_size, void* d_ws, size_t ws_size,
                              hipStream_t stream)
{
    const float* emb    = (const float*)d_in[0];
    const int*   labels = (const int*)d_in[1];
    float*       out    = (float*)d_out;

    char* ws = (char*)d_ws;
    __hip_bfloat16* Ebf = (__hip_bfloat16*)ws;                       // 2 MiB
    float*    sq  = (float*)   (ws + 2 * 1024 * 1024);               // 32 KiB
    unsigned* hp2 = (unsigned*)(ws + 2 * 1024 * 1024 + 32 * 1024);   // 32 KiB
    unsigned* hn2 = (unsigned*)(ws + 2 * 1024 * 1024 + 64 * 1024);   // 32 KiB

    bhtl_prep<<<BATCH / 4, 256, 0, stream>>>(emb, Ebf, sq, hp2, hn2);
    bhtl_main<<<1024, 256, 0, stream>>>(Ebf, sq, labels, hp2, hn2);
    bhtl_final<<<1, 1024, 0, stream>>>(hp2, hn2, out);
}